// Round 8
// baseline (245.699 us; speedup 1.0000x reference)
//
#include <hip/hip_runtime.h>
#include <math.h>

#define N_NODES 50000
#define N_EDGES 1600000
#define IN_DIM 128
#define N_HEADS 8
#define OUT_DIM 16
#define HD 128            // N_HEADS * OUT_DIM
#define NBUCK 784         // dst>>6: 64 nodes per bucket
#define BCAP 2560         // region capacity per bucket (avg ~2041)
#define CHUNK 4096        // edges per bin block
#define BIN_BLOCKS ((N_EDGES + CHUNK - 1) / CHUNK)   // 391
#define NTILE 3125        // 50000/16 M-tiles (exact)
#define PBLK ((NTILE + 3) / 4)                        // 782 proj blocks (4 waves each)
#define TROW 132          // LDS tile row stride in floats (128 + 4 pad)

typedef __attribute__((ext_vector_type(8))) short bf16x8;
typedef __attribute__((ext_vector_type(4))) float f32x4;

__device__ __forceinline__ unsigned short f2bf(float f) {
    union { float f; unsigned int u; } v; v.f = f;
    unsigned int u = v.u;
    unsigned int r = (u + 0x7fffu + ((u >> 16) & 1u)) >> 16;   // RN-even
    return (unsigned short)r;
}

// exclusive scan of arr[0..NBUCK) in place; part[256] scratch; all 256 threads.
__device__ __forceinline__ void scan_nbuck_excl(int* arr, int* part) {
    int t = threadIdx.x;
    int v0 = 0, v1 = 0, v2 = 0, v3 = 0, cs = 0;
    if (t < NBUCK / 4) {
        v0 = arr[4 * t]; v1 = arr[4 * t + 1]; v2 = arr[4 * t + 2]; v3 = arr[4 * t + 3];
        cs = v0 + v1 + v2 + v3;
    }
    part[t] = cs;
    __syncthreads();
    for (int d = 1; d < 256; d <<= 1) {
        int u = (t >= d) ? part[t - d] : 0;
        __syncthreads();
        part[t] += u;
        __syncthreads();
    }
    if (t < NBUCK / 4) {
        int run = part[t] - cs;
        arr[4 * t] = run; run += v0;
        arr[4 * t + 1] = run; run += v1;
        arr[4 * t + 2] = run; run += v2;
        arr[4 * t + 3] = run;
    }
    __syncthreads();
}

// ---------------- prep: W(f32) -> Wb(bf16, same [c][k] layout) + zero counters ----
__global__ void k_prep(const float* __restrict__ W, unsigned short* __restrict__ Wb,
                       int* __restrict__ bucket_cnt, int* __restrict__ ovf_cnt) {
    int g = blockIdx.x * 256 + threadIdx.x;   // 4096 threads over 4096 float4s
    if (g < NBUCK) bucket_cnt[g] = 0;
    if (g == 0) *ovf_cnt = 0;
    if (g >= (HD * IN_DIM) / 4) return;
    float4 v = ((const float4*)W)[g];
    ushort4 us;
    us.x = f2bf(v.x); us.y = f2bf(v.y); us.z = f2bf(v.z); us.w = f2bf(v.w);
    ((ushort4*)Wb)[g] = us;
}

// ---------------- fused: MFMA projection (blocks < PBLK) | edge binning ----------
__global__ __launch_bounds__(256) void k_proj_bin(
    const float* __restrict__ x, const unsigned short* __restrict__ Wb,
    const float* __restrict__ attn_l, const float* __restrict__ attn_r,
    unsigned short* __restrict__ ftb, float* __restrict__ a1, float* __restrict__ a2,
    const int* __restrict__ src, const int* __restrict__ dst,
    unsigned int* __restrict__ region, int* __restrict__ bucket_cnt,
    int* __restrict__ ovf_cnt, unsigned int* __restrict__ ovf) {
    // union: proj 4 wave-private f32 tiles 16x132 (33792 B) | bin 23680 B
    __shared__ __align__(16) char smem[4 * 16 * TROW * 4];
    int tid = threadIdx.x;

    if (blockIdx.x < PBLK) {
        // ---------------- MFMA projection branch ----------------
        int wid  = tid >> 6;
        int tile = blockIdx.x * 4 + wid;
        if (tile >= NTILE) return;           // no barriers in this branch
        int lane = tid & 63;
        int m = lane & 15, q = lane >> 4;
        int node0 = tile * 16;

        // A fragments: x[node0+m][ks*32 + q*8 .. +7], fp32 -> bf16
        const float* xr = x + (size_t)(node0 + m) * IN_DIM + q * 8;
        float4 xa[4][2];
#pragma unroll
        for (int ks = 0; ks < 4; ks++) {
            xa[ks][0] = *(const float4*)(xr + ks * 32);
            xa[ks][1] = *(const float4*)(xr + ks * 32 + 4);
        }
        bf16x8 afr[4];
#pragma unroll
        for (int ks = 0; ks < 4; ks++) {
            afr[ks][0] = (short)f2bf(xa[ks][0].x); afr[ks][1] = (short)f2bf(xa[ks][0].y);
            afr[ks][2] = (short)f2bf(xa[ks][0].z); afr[ks][3] = (short)f2bf(xa[ks][0].w);
            afr[ks][4] = (short)f2bf(xa[ks][1].x); afr[ks][5] = (short)f2bf(xa[ks][1].y);
            afr[ks][6] = (short)f2bf(xa[ks][1].z); afr[ks][7] = (short)f2bf(xa[ks][1].w);
        }

        float* tl = (float*)smem + wid * (16 * TROW);

        // heads loop: B frag = Wb[h*16+m][ks*32 + q*8 .. +7] (original W layout!)
#pragma unroll
        for (int h = 0; h < N_HEADS; h++) {
            const unsigned short* wrow = Wb + (size_t)(h * 16 + m) * IN_DIM + q * 8;
            f32x4 c = {0.f, 0.f, 0.f, 0.f};
#pragma unroll
            for (int ks = 0; ks < 4; ks++) {
                bf16x8 bfr = *(const bf16x8*)(wrow + ks * 32);
                c = __builtin_amdgcn_mfma_f32_16x16x32_bf16(afr[ks], bfr, c, 0, 0, 0);
            }
            // C layout: col = lane&15, row = q*4 + reg  -> stash in LDS tile
#pragma unroll
            for (int r = 0; r < 4; r++)
                tl[(q * 4 + r) * TROW + h * 16 + m] = c[r];
        }

        // a1/a2: lane -> node (lane&15), heads {lane>>4, (lane>>4)+4}
        int nd = lane & 15;
#pragma unroll
        for (int hi = 0; hi < 2; hi++) {
            int hh = (lane >> 4) + hi * 4;
            const float4* rowv = (const float4*)(tl + nd * TROW + hh * 16);
            const float4* alv  = (const float4*)(attn_l + hh * OUT_DIM);
            const float4* arv  = (const float4*)(attn_r + hh * OUT_DIM);
            float sl = 0.f, sr = 0.f;
#pragma unroll
            for (int d4 = 0; d4 < 4; d4++) {
                float4 fv = rowv[d4];
                float4 al = alv[d4];
                float4 ar = arv[d4];
                sl += fv.x * al.x + fv.y * al.y + fv.z * al.z + fv.w * al.w;
                sr += fv.x * ar.x + fv.y * ar.y + fv.z * ar.z + fv.w * ar.w;
            }
            a1[(node0 + nd) * N_HEADS + hh] = sl;
            a2[(node0 + nd) * N_HEADS + hh] = sr;
        }

        // ft store: pass p covers rows p*4+q; lane m covers 8 cols
#pragma unroll
        for (int p = 0; p < 4; p++) {
            int r = p * 4 + q;
            const float* srcp = tl + r * TROW + m * 8;
            float4 f0 = *(const float4*)(srcp);
            float4 f1 = *(const float4*)(srcp + 4);
            ushort4 u0, u1;
            u0.x = f2bf(f0.x); u0.y = f2bf(f0.y); u0.z = f2bf(f0.z); u0.w = f2bf(f0.w);
            u1.x = f2bf(f1.x); u1.y = f2bf(f1.y); u1.z = f2bf(f1.z); u1.w = f2bf(f1.w);
            ushort4* dstp = (ushort4*)(ftb + (size_t)(node0 + r) * HD + m * 8);
            dstp[0] = u0;
            dstp[1] = u1;
        }
    } else {
        // ---------------- binning branch ----------------
        unsigned int* stage = (unsigned int*)smem;          // 16 KB
        int* hist  = (int*)(smem + 16384);                  // NBUCK
        int* delta = (int*)(smem + 19520);                  // NBUCK
        int* part  = (int*)(smem + 22656);                  // 256

        int t = tid;
        int base = (blockIdx.x - PBLK) * CHUNK;
        int nvalid = min(CHUNK, N_EDGES - base);

        for (int i = t; i < NBUCK; i += 256) hist[i] = 0;
        __syncthreads();

        unsigned int mypack[CHUNK / 256];
#pragma unroll
        for (int k = 0; k < CHUNK / 256; k++) {
            int i = t + k * 256;
            if (i < nvalid) {
                int s = src[base + i];
                int d = dst[base + i];
                unsigned int p = ((unsigned int)d << 16) | (unsigned int)s;
                mypack[k] = p;
                atomicAdd(&hist[d >> 6], 1);
            }
        }
        __syncthreads();
        for (int i = t; i < NBUCK; i += 256) {
            int h = hist[i];
            delta[i] = (h > 0) ? atomicAdd(&bucket_cnt[i], h) : 0;
        }
        __syncthreads();
        scan_nbuck_excl(hist, part);            // hist -> local exclusive offsets
        for (int i = t; i < NBUCK; i += 256) delta[i] -= hist[i];
        __syncthreads();
#pragma unroll
        for (int k = 0; k < CHUNK / 256; k++) {
            int i = t + k * 256;
            if (i < nvalid) {
                unsigned int p = mypack[k];
                int slot = atomicAdd(&hist[p >> 22], 1);
                stage[slot] = p;
            }
        }
        __syncthreads();
        for (int i = t; i < nvalid; i += 256) {
            unsigned int p = stage[i];
            int b = p >> 22;
            int pos = delta[b] + i;
            if (pos < BCAP) region[(size_t)b * BCAP + pos] = p;
            else { int o = atomicAdd(ovf_cnt, 1); ovf[o] = p; }
        }
    }
}

// ---------------- per-bucket CSR offsets + placement (784-way parallel) ----------
__global__ __launch_bounds__(256) void k_place(
    const unsigned int* __restrict__ region, const int* __restrict__ bucket_cnt,
    const int* __restrict__ ovf_cnt, const unsigned int* __restrict__ ovf,
    int* __restrict__ offs, unsigned short* __restrict__ esrc) {
    int b = blockIdx.x;
    int t = threadIdx.x;
    __shared__ int sb[NBUCK], part[256];
    __shared__ int hist[64], sc[64], curs[64];

    for (int i = t; i < NBUCK; i += 256) sb[i] = bucket_cnt[i];
    if (t < 64) hist[t] = 0;
    __syncthreads();
    scan_nbuck_excl(sb, part);            // sb -> exclusive bucket prefix

    int truec = bucket_cnt[b];
    int base_b = sb[b];
    int rc = min(truec, BCAP);
    const unsigned int* reg = region + (size_t)b * BCAP;

    for (int i = t; i < rc; i += 256) atomicAdd(&hist[(reg[i] >> 16) & 63], 1);
    int no = 0;
    if (truec > BCAP) {                   // statistically never; correctness fallback
        no = *ovf_cnt;
        for (int i = t; i < no; i += 256)
            if ((int)(ovf[i] >> 22) == b) atomicAdd(&hist[(ovf[i] >> 16) & 63], 1);
    }
    __syncthreads();
    int h = (t < 64) ? hist[t] : 0;
    if (t < 64) sc[t] = h;
    __syncthreads();
    for (int d = 1; d < 64; d <<= 1) {
        int u = (t >= d && t < 64) ? sc[t - d] : 0;
        __syncthreads();
        if (t < 64) sc[t] += u;
        __syncthreads();
    }
    if (t < 64) {
        int pos0 = base_b + sc[t] - h;
        int node = b * 64 + t;
        if (node < N_NODES) offs[node] = pos0;
        curs[t] = pos0;
    }
    if (b == 0 && t == 0) offs[N_NODES] = N_EDGES;
    __syncthreads();
    for (int i = t; i < rc; i += 256) {
        unsigned int p = reg[i];
        int pos = atomicAdd(&curs[(p >> 16) & 63], 1);
        esrc[pos] = (unsigned short)(p & 0xffffu);
    }
    if (truec > BCAP) {
        for (int i = t; i < no; i += 256) {
            unsigned int p = ovf[i];
            if ((int)(p >> 22) == b) {
                int pos = atomicAdd(&curs[(p >> 16) & 63], 1);
                esrc[pos] = (unsigned short)(p & 0xffffu);
            }
        }
    }
}

// ---------------- aggregation: single-pass, one wave per dst node, no LDS --------
// out = (sum_j e_j ft[s_j]) / (sum_j e_j): normalize AFTER accumulation, so no
// separate denominator pass. Every lane visits every edge -> l accumulates the
// full per-head denominator in-register (no cross-lane reduction needed).
// exp() cannot overflow f32 (|logit| <~ 30); identical math to stabilized ref.
__global__ __launch_bounds__(256) void k_aggregate(
    const unsigned short* __restrict__ ftb, const float* __restrict__ a1,
    const float* __restrict__ a2, const int* __restrict__ offs,
    const unsigned short* __restrict__ esrc, float* __restrict__ out) {
    int wid  = threadIdx.x >> 6;
    int lane = threadIdx.x & 63;
    int node = blockIdx.x * 4 + wid;

    int off = offs[node];
    int deg = offs[node + 1] - off;
    int hl = lane >> 3;                       // head for this lane's dim pair
    float a2h = a2[node * N_HEADS + hl];

    const unsigned short* ep = esrc + off;
    float accx = 0.f, accy = 0.f, l = 0.f;

    for (int base = 0; base < deg; base += 8) {
        int mye = base + (lane & 7);
        int sv = (mye < deg) ? (int)ep[mye] : 0;   // coalesced 16 B, 8-way dup
#pragma unroll
        for (int k = 0; k < 8; k++) {
            if (base + k < deg) {                  // wave-uniform guard
                int s = __shfl(sv, k);
                float a1v = a1[s * N_HEADS + hl];  // 32 B per edge, 8-way bcast
                unsigned int p = *(const unsigned int*)(ftb + (size_t)s * HD + lane * 2);
                float t = a1v + a2h;
                t = t > 0.f ? t : 0.2f * t;
                float e = __expf(t);
                l += e;
                accx = fmaf(e, __uint_as_float(p << 16), accx);
                accy = fmaf(e, __uint_as_float(p & 0xffff0000u), accy);
            }
        }
    }

    float invl = (deg > 0) ? 1.f / l : 0.f;
    float2 o; o.x = accx * invl; o.y = accy * invl;
    *(float2*)(out + (size_t)node * HD + lane * 2) = o;
}

// ---------------- host launcher ----------------
extern "C" void kernel_launch(void* const* d_in, const int* in_sizes, int n_in,
                              void* d_out, int out_size, void* d_ws, size_t ws_size,
                              hipStream_t stream) {
    const float* x      = (const float*)d_in[0];
    const float* W      = (const float*)d_in[1];
    const float* attn_l = (const float*)d_in[2];
    const float* attn_r = (const float*)d_in[3];
    const int*   src    = (const int*)d_in[4];
    const int*   dst    = (const int*)d_in[5];
    float* out = (float*)d_out;

    char* ws = (char*)d_ws;
    size_t o = 0;
    auto alloc = [&](size_t bytes) -> char* {
        char* p = ws + o;
        o = (o + bytes + 255) & ~(size_t)255;
        return p;
    };
    unsigned short* ftb  = (unsigned short*)alloc((size_t)N_NODES * HD * 2);   // 12.8 MB
    float* a1            = (float*)alloc((size_t)N_NODES * N_HEADS * 4);
    float* a2            = (float*)alloc((size_t)N_NODES * N_HEADS * 4);
    unsigned short* Wb   = (unsigned short*)alloc((size_t)HD * IN_DIM * 2);    // 32 KB
    unsigned int* region = (unsigned int*)alloc((size_t)NBUCK * BCAP * 4);     // 8.0 MB
    int* bucket_cnt      = (int*)alloc((size_t)NBUCK * 4);
    int* ovf_cnt         = (int*)alloc(4);
    unsigned int* ovf    = (unsigned int*)alloc((size_t)N_EDGES * 4);          // 6.4 MB
    int* offs            = (int*)alloc((size_t)(N_NODES + 1) * 4);
    unsigned short* esrc = (unsigned short*)alloc((size_t)N_EDGES * 2);        // 3.2 MB

    (void)in_sizes; (void)n_in; (void)out_size; (void)ws_size;

    k_prep<<<16, 256, 0, stream>>>(W, Wb, bucket_cnt, ovf_cnt);
    k_proj_bin<<<PBLK + BIN_BLOCKS, 256, 0, stream>>>(
        x, Wb, attn_l, attn_r, ftb, a1, a2,
        src, dst, region, bucket_cnt, ovf_cnt, ovf);
    k_place<<<NBUCK, 256, 0, stream>>>(region, bucket_cnt, ovf_cnt, ovf, offs, esrc);
    k_aggregate<<<N_NODES / 4, 256, 0, stream>>>(ftb, a1, a2, offs, esrc, out);
}

// Round 9
// 199.915 us; speedup vs baseline: 1.2290x; 1.2290x over previous
//
#include <hip/hip_runtime.h>
#include <math.h>

#define N_NODES 50000
#define N_EDGES 1600000
#define IN_DIM 128
#define N_HEADS 8
#define OUT_DIM 16
#define HD 128            // N_HEADS * OUT_DIM
#define NBUCK 784         // dst>>6: 64 nodes per bucket
#define BCAP 2560         // region capacity per bucket (avg ~2041)
#define CHUNK 4096        // edges per bin block
#define BIN_BLOCKS ((N_EDGES + CHUNK - 1) / CHUNK)   // 391
#define NTILE 3125        // 50000/16 M-tiles (exact)
#define PBLK ((NTILE + 3) / 4)                        // 782 proj blocks (4 waves each)
#define TROW 132          // LDS tile row stride in floats (128 + 4 pad)

typedef __attribute__((ext_vector_type(8))) short bf16x8;
typedef __attribute__((ext_vector_type(4))) float f32x4;

__device__ __forceinline__ unsigned short f2bf(float f) {
    union { float f; unsigned int u; } v; v.f = f;
    unsigned int u = v.u;
    unsigned int r = (u + 0x7fffu + ((u >> 16) & 1u)) >> 16;   // RN-even
    return (unsigned short)r;
}

// exclusive scan of arr[0..NBUCK) in place; part[256] scratch; all 256 threads.
__device__ __forceinline__ void scan_nbuck_excl(int* arr, int* part) {
    int t = threadIdx.x;
    int v0 = 0, v1 = 0, v2 = 0, v3 = 0, cs = 0;
    if (t < NBUCK / 4) {
        v0 = arr[4 * t]; v1 = arr[4 * t + 1]; v2 = arr[4 * t + 2]; v3 = arr[4 * t + 3];
        cs = v0 + v1 + v2 + v3;
    }
    part[t] = cs;
    __syncthreads();
    for (int d = 1; d < 256; d <<= 1) {
        int u = (t >= d) ? part[t - d] : 0;
        __syncthreads();
        part[t] += u;
        __syncthreads();
    }
    if (t < NBUCK / 4) {
        int run = part[t] - cs;
        arr[4 * t] = run; run += v0;
        arr[4 * t + 1] = run; run += v1;
        arr[4 * t + 2] = run; run += v2;
        arr[4 * t + 3] = run;
    }
    __syncthreads();
}

// ---------------- prep: W(f32) -> Wb(bf16, same [c][k] layout) + zero counters ----
__global__ void k_prep(const float* __restrict__ W, unsigned short* __restrict__ Wb,
                       int* __restrict__ bucket_cnt, int* __restrict__ ovf_cnt) {
    int g = blockIdx.x * 256 + threadIdx.x;   // 4096 threads over 4096 float4s
    if (g < NBUCK) bucket_cnt[g] = 0;
    if (g == 0) *ovf_cnt = 0;
    if (g >= (HD * IN_DIM) / 4) return;
    float4 v = ((const float4*)W)[g];
    ushort4 us;
    us.x = f2bf(v.x); us.y = f2bf(v.y); us.z = f2bf(v.z); us.w = f2bf(v.w);
    ((ushort4*)Wb)[g] = us;
}

// ---------------- fused: MFMA projection (blocks < PBLK) | edge binning ----------
__global__ __launch_bounds__(256) void k_proj_bin(
    const float* __restrict__ x, const unsigned short* __restrict__ Wb,
    const float* __restrict__ attn_l, const float* __restrict__ attn_r,
    unsigned short* __restrict__ ftb, float* __restrict__ a1, float* __restrict__ a2,
    const int* __restrict__ src, const int* __restrict__ dst,
    unsigned int* __restrict__ region, int* __restrict__ bucket_cnt,
    int* __restrict__ ovf_cnt, unsigned int* __restrict__ ovf) {
    // union: proj 4 wave-private f32 tiles 16x132 (33792 B) | bin 23680 B
    __shared__ __align__(16) char smem[4 * 16 * TROW * 4];
    int tid = threadIdx.x;

    if (blockIdx.x < PBLK) {
        // ---------------- MFMA projection branch ----------------
        int wid  = tid >> 6;
        int tile = blockIdx.x * 4 + wid;
        if (tile >= NTILE) return;           // no barriers in this branch
        int lane = tid & 63;
        int m = lane & 15, q = lane >> 4;
        int node0 = tile * 16;

        // A fragments: x[node0+m][ks*32 + q*8 .. +7], fp32 -> bf16
        const float* xr = x + (size_t)(node0 + m) * IN_DIM + q * 8;
        float4 xa[4][2];
#pragma unroll
        for (int ks = 0; ks < 4; ks++) {
            xa[ks][0] = *(const float4*)(xr + ks * 32);
            xa[ks][1] = *(const float4*)(xr + ks * 32 + 4);
        }
        bf16x8 afr[4];
#pragma unroll
        for (int ks = 0; ks < 4; ks++) {
            afr[ks][0] = (short)f2bf(xa[ks][0].x); afr[ks][1] = (short)f2bf(xa[ks][0].y);
            afr[ks][2] = (short)f2bf(xa[ks][0].z); afr[ks][3] = (short)f2bf(xa[ks][0].w);
            afr[ks][4] = (short)f2bf(xa[ks][1].x); afr[ks][5] = (short)f2bf(xa[ks][1].y);
            afr[ks][6] = (short)f2bf(xa[ks][1].z); afr[ks][7] = (short)f2bf(xa[ks][1].w);
        }

        float* tl = (float*)smem + wid * (16 * TROW);

        // heads loop: B frag = Wb[h*16+m][ks*32 + q*8 .. +7] (original W layout!)
#pragma unroll
        for (int h = 0; h < N_HEADS; h++) {
            const unsigned short* wrow = Wb + (size_t)(h * 16 + m) * IN_DIM + q * 8;
            f32x4 c = {0.f, 0.f, 0.f, 0.f};
#pragma unroll
            for (int ks = 0; ks < 4; ks++) {
                bf16x8 bfr = *(const bf16x8*)(wrow + ks * 32);
                c = __builtin_amdgcn_mfma_f32_16x16x32_bf16(afr[ks], bfr, c, 0, 0, 0);
            }
            // C layout: col = lane&15, row = q*4 + reg  -> stash in LDS tile
#pragma unroll
            for (int r = 0; r < 4; r++)
                tl[(q * 4 + r) * TROW + h * 16 + m] = c[r];
        }

        // a1/a2: lane -> node (lane&15), heads {lane>>4, (lane>>4)+4}
        int nd = lane & 15;
#pragma unroll
        for (int hi = 0; hi < 2; hi++) {
            int hh = (lane >> 4) + hi * 4;
            const float4* rowv = (const float4*)(tl + nd * TROW + hh * 16);
            const float4* alv  = (const float4*)(attn_l + hh * OUT_DIM);
            const float4* arv  = (const float4*)(attn_r + hh * OUT_DIM);
            float sl = 0.f, sr = 0.f;
#pragma unroll
            for (int d4 = 0; d4 < 4; d4++) {
                float4 fv = rowv[d4];
                float4 al = alv[d4];
                float4 ar = arv[d4];
                sl += fv.x * al.x + fv.y * al.y + fv.z * al.z + fv.w * al.w;
                sr += fv.x * ar.x + fv.y * ar.y + fv.z * ar.z + fv.w * ar.w;
            }
            a1[(node0 + nd) * N_HEADS + hh] = sl;
            a2[(node0 + nd) * N_HEADS + hh] = sr;
        }

        // ft store: pass p covers rows p*4+q; lane m covers 8 cols
#pragma unroll
        for (int p = 0; p < 4; p++) {
            int r = p * 4 + q;
            const float* srcp = tl + r * TROW + m * 8;
            float4 f0 = *(const float4*)(srcp);
            float4 f1 = *(const float4*)(srcp + 4);
            ushort4 u0, u1;
            u0.x = f2bf(f0.x); u0.y = f2bf(f0.y); u0.z = f2bf(f0.z); u0.w = f2bf(f0.w);
            u1.x = f2bf(f1.x); u1.y = f2bf(f1.y); u1.z = f2bf(f1.z); u1.w = f2bf(f1.w);
            ushort4* dstp = (ushort4*)(ftb + (size_t)(node0 + r) * HD + m * 8);
            dstp[0] = u0;
            dstp[1] = u1;
        }
    } else {
        // ---------------- binning branch ----------------
        unsigned int* stage = (unsigned int*)smem;          // 16 KB
        int* hist  = (int*)(smem + 16384);                  // NBUCK
        int* delta = (int*)(smem + 19520);                  // NBUCK
        int* part  = (int*)(smem + 22656);                  // 256

        int t = tid;
        int base = (blockIdx.x - PBLK) * CHUNK;
        int nvalid = min(CHUNK, N_EDGES - base);

        for (int i = t; i < NBUCK; i += 256) hist[i] = 0;
        __syncthreads();

        unsigned int mypack[CHUNK / 256];
#pragma unroll
        for (int k = 0; k < CHUNK / 256; k++) {
            int i = t + k * 256;
            if (i < nvalid) {
                int s = src[base + i];
                int d = dst[base + i];
                unsigned int p = ((unsigned int)d << 16) | (unsigned int)s;
                mypack[k] = p;
                atomicAdd(&hist[d >> 6], 1);
            }
        }
        __syncthreads();
        for (int i = t; i < NBUCK; i += 256) {
            int h = hist[i];
            delta[i] = (h > 0) ? atomicAdd(&bucket_cnt[i], h) : 0;
        }
        __syncthreads();
        scan_nbuck_excl(hist, part);            // hist -> local exclusive offsets
        for (int i = t; i < NBUCK; i += 256) delta[i] -= hist[i];
        __syncthreads();
#pragma unroll
        for (int k = 0; k < CHUNK / 256; k++) {
            int i = t + k * 256;
            if (i < nvalid) {
                unsigned int p = mypack[k];
                int slot = atomicAdd(&hist[p >> 22], 1);
                stage[slot] = p;
            }
        }
        __syncthreads();
        for (int i = t; i < nvalid; i += 256) {
            unsigned int p = stage[i];
            int b = p >> 22;
            int pos = delta[b] + i;
            if (pos < BCAP) region[(size_t)b * BCAP + pos] = p;
            else { int o = atomicAdd(ovf_cnt, 1); ovf[o] = p; }
        }
    }
}

// ---------------- per-bucket CSR offsets + placement (784-way parallel) ----------
__global__ __launch_bounds__(256) void k_place(
    const unsigned int* __restrict__ region, const int* __restrict__ bucket_cnt,
    const int* __restrict__ ovf_cnt, const unsigned int* __restrict__ ovf,
    int* __restrict__ offs, unsigned short* __restrict__ esrc) {
    int b = blockIdx.x;
    int t = threadIdx.x;
    __shared__ int sb[NBUCK], part[256];
    __shared__ int hist[64], sc[64], curs[64];

    for (int i = t; i < NBUCK; i += 256) sb[i] = bucket_cnt[i];
    if (t < 64) hist[t] = 0;
    __syncthreads();
    scan_nbuck_excl(sb, part);            // sb -> exclusive bucket prefix

    int truec = bucket_cnt[b];
    int base_b = sb[b];
    int rc = min(truec, BCAP);
    const unsigned int* reg = region + (size_t)b * BCAP;

    for (int i = t; i < rc; i += 256) atomicAdd(&hist[(reg[i] >> 16) & 63], 1);
    int no = 0;
    if (truec > BCAP) {                   // statistically never; correctness fallback
        no = *ovf_cnt;
        for (int i = t; i < no; i += 256)
            if ((int)(ovf[i] >> 22) == b) atomicAdd(&hist[(ovf[i] >> 16) & 63], 1);
    }
    __syncthreads();
    int h = (t < 64) ? hist[t] : 0;
    if (t < 64) sc[t] = h;
    __syncthreads();
    for (int d = 1; d < 64; d <<= 1) {
        int u = (t >= d && t < 64) ? sc[t - d] : 0;
        __syncthreads();
        if (t < 64) sc[t] += u;
        __syncthreads();
    }
    if (t < 64) {
        int pos0 = base_b + sc[t] - h;
        int node = b * 64 + t;
        if (node < N_NODES) offs[node] = pos0;
        curs[t] = pos0;
    }
    if (b == 0 && t == 0) offs[N_NODES] = N_EDGES;
    __syncthreads();
    for (int i = t; i < rc; i += 256) {
        unsigned int p = reg[i];
        int pos = atomicAdd(&curs[(p >> 16) & 63], 1);
        esrc[pos] = (unsigned short)(p & 0xffffu);
    }
    if (truec > BCAP) {
        for (int i = t; i < no; i += 256) {
            unsigned int p = ovf[i];
            if ((int)(p >> 22) == b) {
                int pos = atomicAdd(&curs[(p >> 16) & 63], 1);
                esrc[pos] = (unsigned short)(p & 0xffffu);
            }
        }
    }
}

// ---------------- aggregation: single-pass, batched-16 for MLP ----------------
// out = (sum_j e_j ft[s_j]) / (sum_j e_j). Every lane visits every edge, so l
// accumulates the per-head denominator in-register. Per 16-edge chunk: stage
// all 16 src indices, then ISSUE all 32 loads (16 a1 + 16 ft rows) into arrays
// BEFORE any consumer -> 16 independent 256 B gathers in flight per wave.
__global__ __launch_bounds__(256) void k_aggregate(
    const unsigned short* __restrict__ ftb, const float* __restrict__ a1,
    const float* __restrict__ a2, const int* __restrict__ offs,
    const unsigned short* __restrict__ esrc, float* __restrict__ out) {
    int wid  = threadIdx.x >> 6;
    int lane = threadIdx.x & 63;
    int node = blockIdx.x * 4 + wid;

    int off = offs[node];
    int deg = offs[node + 1] - off;
    int hl = lane >> 3;                       // head for this lane's dim pair
    float a2h = a2[node * N_HEADS + hl];
    int dimoff = lane * 2;

    const unsigned short* ep = esrc + off;
    float accx = 0.f, accy = 0.f, l = 0.f;

    int nfull = deg & ~15;
    for (int base = 0; base < nfull; base += 16) {
        int sv = (int)ep[base + (lane & 15)];      // coalesced 32 B, 4-way dup
        int s[16];
#pragma unroll
        for (int k = 0; k < 16; k++) s[k] = __shfl(sv, k);   // wave-uniform bases
        float a1v[16];
        unsigned int p[16];
#pragma unroll
        for (int k = 0; k < 16; k++) {
            a1v[k] = a1[s[k] * N_HEADS + hl];
            p[k]   = *(const unsigned int*)(ftb + (size_t)s[k] * HD + dimoff);
        }
#pragma unroll
        for (int k = 0; k < 16; k++) {
            float t = a1v[k] + a2h;
            t = t > 0.f ? t : 0.2f * t;
            float e = __expf(t);
            l += e;
            accx = fmaf(e, __uint_as_float(p[k] << 16), accx);
            accy = fmaf(e, __uint_as_float(p[k] & 0xffff0000u), accy);
        }
    }
    if (nfull < deg) {                            // tail: <16 edges, uniform guards
        int mye = nfull + (lane & 15);
        int sv = (mye < deg) ? (int)ep[mye] : 0;
#pragma unroll
        for (int k = 0; k < 16; k++) {
            if (nfull + k < deg) {
                int s = __shfl(sv, k);
                float a1v = a1[s * N_HEADS + hl];
                unsigned int p = *(const unsigned int*)(ftb + (size_t)s * HD + dimoff);
                float t = a1v + a2h;
                t = t > 0.f ? t : 0.2f * t;
                float e = __expf(t);
                l += e;
                accx = fmaf(e, __uint_as_float(p << 16), accx);
                accy = fmaf(e, __uint_as_float(p & 0xffff0000u), accy);
            }
        }
    }

    float invl = (deg > 0) ? 1.f / l : 0.f;
    float2 o; o.x = accx * invl; o.y = accy * invl;
    *(float2*)(out + (size_t)node * HD + dimoff) = o;
}

// ---------------- host launcher ----------------
extern "C" void kernel_launch(void* const* d_in, const int* in_sizes, int n_in,
                              void* d_out, int out_size, void* d_ws, size_t ws_size,
                              hipStream_t stream) {
    const float* x      = (const float*)d_in[0];
    const float* W      = (const float*)d_in[1];
    const float* attn_l = (const float*)d_in[2];
    const float* attn_r = (const float*)d_in[3];
    const int*   src    = (const int*)d_in[4];
    const int*   dst    = (const int*)d_in[5];
    float* out = (float*)d_out;

    char* ws = (char*)d_ws;
    size_t o = 0;
    auto alloc = [&](size_t bytes) -> char* {
        char* p = ws + o;
        o = (o + bytes + 255) & ~(size_t)255;
        return p;
    };
    unsigned short* ftb  = (unsigned short*)alloc((size_t)N_NODES * HD * 2);   // 12.8 MB
    float* a1            = (float*)alloc((size_t)N_NODES * N_HEADS * 4);
    float* a2            = (float*)alloc((size_t)N_NODES * N_HEADS * 4);
    unsigned short* Wb   = (unsigned short*)alloc((size_t)HD * IN_DIM * 2);    // 32 KB
    unsigned int* region = (unsigned int*)alloc((size_t)NBUCK * BCAP * 4);     // 8.0 MB
    int* bucket_cnt      = (int*)alloc((size_t)NBUCK * 4);
    int* ovf_cnt         = (int*)alloc(4);
    unsigned int* ovf    = (unsigned int*)alloc((size_t)N_EDGES * 4);          // 6.4 MB
    int* offs            = (int*)alloc((size_t)(N_NODES + 1) * 4);
    unsigned short* esrc = (unsigned short*)alloc((size_t)N_EDGES * 2);        // 3.2 MB

    (void)in_sizes; (void)n_in; (void)out_size; (void)ws_size;

    k_prep<<<16, 256, 0, stream>>>(W, Wb, bucket_cnt, ovf_cnt);
    k_proj_bin<<<PBLK + BIN_BLOCKS, 256, 0, stream>>>(
        x, Wb, attn_l, attn_r, ftb, a1, a2,
        src, dst, region, bucket_cnt, ovf_cnt, ovf);
    k_place<<<NBUCK, 256, 0, stream>>>(region, bucket_cnt, ovf_cnt, ovf, offs, esrc);
    k_aggregate<<<N_NODES / 4, 256, 0, stream>>>(ftb, a1, a2, offs, esrc, out);
}